// Round 16
// baseline (553.970 us; speedup 1.0000x reference)
//
#include <hip/hip_runtime.h>

// Problem constants
#define N_NODES 100000
#define N_EDGES 1600000
#define EPAD    (N_EDGES + NB * BW)      // rec capacity w/ per-bucket slack
#define HDIM    64
#define NGRAPH  64
#define BW      256                      // bucket width (nodes); shift = 8
#define NB      391                      // ceil(N_NODES / BW)
#define NBLK    256                      // edge-pass blocks
#define CHUNK   ((N_EDGES + NBLK - 1) / NBLK)
#define NGROUPS (N_NODES / 8)            // 12500 fused-layer blocks

// native fp16, no hip_fp16 header
typedef _Float16 h16;
typedef _Float16 h16x4 __attribute__((ext_vector_type(4)));
typedef _Float16 h16x8 __attribute__((ext_vector_type(8)));
typedef float    f32x4 __attribute__((ext_vector_type(4)));

// ----------------------------------------- K1: per-(block,bucket) edge counts
__global__ __launch_bounds__(512) void bucket_count(const int* __restrict__ ei,
                                                    int* __restrict__ cntTabA,
                                                    int* __restrict__ cntTabT) {
    __shared__ int cA[NB], cT[NB];
    const int tid = threadIdx.x;
    for (int i = tid; i < NB; i += 512) { cA[i] = 0; cT[i] = 0; }
    __syncthreads();
    const int e0 = blockIdx.x * CHUNK, e1 = min(e0 + CHUNK, N_EDGES);
    for (int e = e0 + tid; e < e1; e += 512) {
        int r = ei[e];
        int c = ei[N_EDGES + e];
        atomicAdd(&cA[r >> 8], 1);
        atomicAdd(&cT[c >> 8], 1);
    }
    __syncthreads();
    for (int b = tid; b < NB; b += 512) {
        cntTabA[b * NBLK + blockIdx.x] = cA[b];
        cntTabT[b * NBLK + blockIdx.x] = cT[b];
    }
}

// ---------------- K2a: per-bucket LDS scan of the 256 per-block counts
__global__ __launch_bounds__(256) void chunk_scan(int* __restrict__ cntTabA,
                                                  int* __restrict__ cntTabT,
                                                  int* __restrict__ tot) {
    __shared__ int s[256];
    const int b = blockIdx.x, d = blockIdx.y, tid = threadIdx.x;
    int* tab = d ? cntTabT : cntTabA;
    int v = tab[b * NBLK + tid];
    s[tid] = v;
    __syncthreads();
    for (int off = 1; off < 256; off <<= 1) {
        int t = (tid >= off) ? s[tid - off] : 0;
        __syncthreads();
        s[tid] += t;
        __syncthreads();
    }
    tab[b * NBLK + tid] = s[tid] - v;       // exclusive within bucket
    if (tid == 255) tot[d * 512 + b] = s[255];
}

// ---------------- K2b: bucket-start scan (both dirs, one block, parallel)
__global__ __launch_bounds__(512) void start_scan(const int* __restrict__ tot,
                                                  int* __restrict__ bktStartA,
                                                  int* __restrict__ bktStartT) {
    __shared__ int s[512];
    const int tid = threadIdx.x;
    int v = (tid < NB) ? tot[tid] : 0;
    s[tid] = v;
    __syncthreads();
    for (int off = 1; off < 512; off <<= 1) {
        int t = (tid >= off) ? s[tid - off] : 0;
        __syncthreads();
        s[tid] += t;
        __syncthreads();
    }
    if (tid < NB) bktStartA[tid] = s[tid] - v;
    if (tid == 0) bktStartA[NB] = N_EDGES;
    __syncthreads();
    int v2 = (tid < NB) ? tot[512 + tid] : 0;
    s[tid] = v2;
    __syncthreads();
    for (int off = 1; off < 512; off <<= 1) {
        int t = (tid >= off) ? s[tid - off] : 0;
        __syncthreads();
        s[tid] += t;
        __syncthreads();
    }
    if (tid < NB) bktStartT[tid] = s[tid] - v2;
    if (tid == 0) bktStartT[NB] = N_EDGES;
}

// --------------------------- K3: bucketize write (bases pre-reserved)
__global__ __launch_bounds__(512) void bucketize_write(const int* __restrict__ ei,
                                                       const int* __restrict__ cntTabA,
                                                       const int* __restrict__ cntTabT,
                                                       const int* __restrict__ bktStartA,
                                                       const int* __restrict__ bktStartT,
                                                       int2* __restrict__ bktA,
                                                       int2* __restrict__ bktT) {
    __shared__ int bA[NB], bT[NB];
    const int tid = threadIdx.x;
    for (int i = tid; i < NB; i += 512) {
        bA[i] = bktStartA[i] + cntTabA[i * NBLK + blockIdx.x];
        bT[i] = bktStartT[i] + cntTabT[i * NBLK + blockIdx.x];
    }
    __syncthreads();
    const int e0 = blockIdx.x * CHUNK, e1 = min(e0 + CHUNK, N_EDGES);
    for (int e = e0 + tid; e < e1; e += 512) {
        int r = ei[e];
        int c = ei[N_EDGES + e];
        int pA = atomicAdd(&bA[r >> 8], 1);
        bktA[pA] = make_int2(r, c);          // (target, source)
        int pT = atomicAdd(&bT[c >> 8], 1);
        bktT[pT] = make_int2(c, r);          // (target, source)
    }
}

// ----- K4: per-bucket degrees + rsqrt + padded node ptrs (slack allocation)
__global__ __launch_bounds__(256) void bucket_deg_ptr(
        const int* __restrict__ bktStartA, const int* __restrict__ bktStartT,
        const int2* __restrict__ bktA, const int2* __restrict__ bktT,
        int* __restrict__ deg_out, int* __restrict__ deg_in,
        float* __restrict__ r_out, float* __restrict__ r_in,
        int* __restrict__ rowptrP, int* __restrict__ colptrP) {
    __shared__ int c[BW];
    __shared__ int s[256];
    const int b = blockIdx.x, d = blockIdx.y, tid = threadIdx.x;
    const int* bs = d ? bktStartT : bktStartA;
    const int2* bkt = d ? bktT : bktA;
    int* deg = d ? deg_in : deg_out;
    float* rr = d ? r_in : r_out;
    int* ptr = d ? colptrP : rowptrP;
    const int node0 = b * BW;
    c[tid] = 0;
    __syncthreads();
    const int i0 = bs[b], i1 = bs[b + 1];
    for (int i = i0 + tid; i < i1; i += 256) atomicAdd(&c[bkt[i].x - node0], 1);
    __syncthreads();
    int n = node0 + tid, dg = c[tid];
    int pad = dg + (dg & 1);
    if (n >= N_NODES) pad = 0;
    s[tid] = pad;
    __syncthreads();
    for (int off = 1; off < 256; off <<= 1) {
        int t = (tid >= off) ? s[tid - off] : 0;
        __syncthreads();
        s[tid] += t;
        __syncthreads();
    }
    if (n < N_NODES) {
        deg[n] = dg;
        rr[n] = dg > 0 ? rsqrtf((float)dg) : 0.0f;
        ptr[n] = i0 + b * BW + (s[tid] - pad);
    }
}

// ------------------------------------- K7: within-bucket counting scatter
// record payload: (src<<7, w fp32 bits) — 128B rows everywhere
__global__ __launch_bounds__(512) void bucket_scatter(
        const int* __restrict__ rowptrP, const int* __restrict__ colptrP,
        const float* __restrict__ r_out, const float* __restrict__ r_in,
        const int* __restrict__ bktStartA, const int* __restrict__ bktStartT,
        const int2* __restrict__ bktA, const int2* __restrict__ bktT,
        int2* __restrict__ recA, int2* __restrict__ recT) {
    __shared__ int cur[BW];
    __shared__ float rwt[BW];
    const int b = blockIdx.x, d = blockIdx.y, tid = threadIdx.x;
    const int* ptr = d ? colptrP : rowptrP;
    const float* rt = d ? r_in : r_out;       // target-side scale (bucket-local)
    const float* rs = d ? r_out : r_in;       // source-side scale (gathered)
    const int* bs = d ? bktStartT : bktStartA;
    const int2* bkt = d ? bktT : bktA;
    int2* rec = d ? recT : recA;
    const int node0 = b * BW;
    if (tid < BW) {
        int n = node0 + tid;
        cur[tid] = (n < N_NODES) ? ptr[n] : 0;
        rwt[tid] = (n < N_NODES) ? rt[n] : 0.0f;
    }
    __syncthreads();
    const int i0 = bs[b], i1 = bs[b + 1];
    for (int i = i0 + tid; i < i1; i += 512) {
        int2 e = bkt[i];
        float w = rwt[e.x - node0] * rs[e.y];
        int p = atomicAdd(&cur[e.x - node0], 1);
        rec[p] = make_int2(e.y << 7, __float_as_int(w));   // byte offset, weight
    }
}

// ---------------------------------------- x -> fp16 cast (+ zero pooled g)
__global__ __launch_bounds__(256) void cast_kernel(const float4* __restrict__ x,
                                                   h16x4* __restrict__ xh,
                                                   unsigned* __restrict__ g) {
    if (blockIdx.x == 0) {
        for (int j = threadIdx.x; j < NGRAPH * HDIM; j += 256) g[j] = 0u;
    }
    int i = blockIdx.x * 256 + threadIdx.x;   // over N*64/4 float4s
    if (i < N_NODES * 16) {
        float4 v = x[i];
        h16x4 o;
        o.x = (h16)v.x; o.y = (h16)v.y; o.z = (h16)v.z; o.w = (h16)v.w;
        xh[i] = o;
    }
}

// ------------------------- weight prep: WT[l][f][k] = 0.5*Wcat^T fp16, bcat
__global__ __launch_bounds__(256) void wprep_kernel(
        const float* __restrict__ w1s, const float* __restrict__ w1d,
        const float* __restrict__ w2s, const float* __restrict__ w2d,
        const float* __restrict__ w3s, const float* __restrict__ w3d,
        const float* __restrict__ b1s, const float* __restrict__ b1d,
        const float* __restrict__ b2s, const float* __restrict__ b2d,
        const float* __restrict__ b3s, const float* __restrict__ b3d,
        h16* __restrict__ WT, float* __restrict__ bc) {
    const int l = blockIdx.y;
    const float* ws = l == 0 ? w1s : l == 1 ? w2s : w3s;
    const float* wd = l == 0 ? w1d : l == 1 ? w2d : w3d;
    int e = blockIdx.x * 256 + threadIdx.x;
    if (e < 8192) {
        int f = e >> 7, k = e & 127;
        float v = (k < 64) ? ws[k * 64 + f] : wd[(k - 64) * 64 + f];
        WT[l * 8192 + f * 128 + k] = (h16)(0.5f * v);
    }
    if (blockIdx.x == 0 && threadIdx.x < 64) {
        const float* bs = l == 0 ? b1s : l == 1 ? b2s : b3s;
        const float* bd = l == 0 ? b1d : l == 1 ? b2d : b3d;
        bc[l * 64 + threadIdx.x] = 0.5f * (bs[threadIdx.x] + bd[threadIdx.x]);
    }
}

// ------------------------------------------------ fused layer
__device__ __forceinline__ void fma4h(float4& a, float w, h16x4 f) {
    a.x = fmaf(w, (float)f.x, a.x);
    a.y = fmaf(w, (float)f.y, a.y);
    a.z = fmaf(w, (float)f.z, a.z);
    a.w = fmaf(w, (float)f.w, a.w);
}

__device__ __forceinline__ float4 red_s(float4 v) {
    v.x += __shfl_xor(v.x, 16); v.y += __shfl_xor(v.y, 16);
    v.z += __shfl_xor(v.z, 16); v.w += __shfl_xor(v.w, 16);
    v.x += __shfl_xor(v.x, 32); v.y += __shfl_xor(v.y, 32);
    v.z += __shfl_xor(v.z, 32); v.w += __shfl_xor(v.w, 32);
    return v;
}

__device__ __forceinline__ h16x4 ld_h4(const char* __restrict__ p) {
    return *(const h16x4*)p;
}

// per-wave aggregation; lane (q,s): q = feature quad, s = edge-pair slot.
// records are (src byte-offset<<7, w) int2; node runs start 16B-aligned.
__device__ __forceinline__ float4 agg_dir(const char* __restrict__ hb,
                                          const int2* __restrict__ rec,
                                          int start, int deg, int qb, int s) {
    float4 a0 = {0.f,0.f,0.f,0.f}, a1 = {0.f,0.f,0.f,0.f};
    float4 a2 = {0.f,0.f,0.f,0.f}, a3 = {0.f,0.f,0.f,0.f};
    const int4* rec4 = (const int4*)(rec + start);
    int k = 0;
    for (; k + 16 <= deg; k += 16) {
        int4 p0 = rec4[(k >> 1) + s];         // edges k+2s, k+2s+1
        int4 p1 = rec4[(k >> 1) + 4 + s];     // edges k+8+2s, k+8+2s+1
        h16x4 f0 = ld_h4(hb + p0.x + qb);
        h16x4 f1 = ld_h4(hb + p0.z + qb);
        h16x4 f2 = ld_h4(hb + p1.x + qb);
        h16x4 f3 = ld_h4(hb + p1.z + qb);
        fma4h(a0, __int_as_float(p0.y), f0);
        fma4h(a1, __int_as_float(p0.w), f1);
        fma4h(a2, __int_as_float(p1.y), f2);
        fma4h(a3, __int_as_float(p1.w), f3);
    }
    if (k + 8 <= deg) {
        int4 p = rec4[(k >> 1) + s];
        h16x4 f0 = ld_h4(hb + p.x + qb);
        h16x4 f1 = ld_h4(hb + p.z + qb);
        fma4h(a0, __int_as_float(p.y), f0);
        fma4h(a1, __int_as_float(p.w), f1);
        k += 8;
    }
    int r = deg - k;                          // 0..7 remaining
    if (2 * s < r) {
        int4 p = rec4[(k >> 1) + s];
        h16x4 f0 = ld_h4(hb + p.x + qb);
        fma4h(a2, __int_as_float(p.y), f0);
        if (2 * s + 1 < r) {
            h16x4 f1 = ld_h4(hb + p.z + qb);
            fma4h(a3, __int_as_float(p.w), f1);
        }
    }
    a0.x += a1.x; a0.y += a1.y; a0.z += a1.z; a0.w += a1.w;
    a2.x += a3.x; a2.y += a3.y; a2.z += a3.z; a2.w += a3.w;
    a0.x += a2.x; a0.y += a2.y; a0.z += a2.z; a0.w += a2.w;
    return red_s(a0);
}

// Fused layer: 16 waves = 8 (node,dir) aggregations -> LDS -> 4 waves do the
// 16x16 MFMA tile (rows 8..15 garbage, not stored) -> h (128B rows) or pool.
#define ASTRIDE 132                       // h16 elems per LDS acc row (padded)
__global__ __launch_bounds__(1024) void layer_fused(
        const char* __restrict__ h_in, char* __restrict__ h_out,
        const int* __restrict__ rowptrP, const int* __restrict__ deg_out,
        const int2* __restrict__ recA,
        const int* __restrict__ colptrP, const int* __restrict__ deg_in,
        const int2* __restrict__ recT,
        const h16* __restrict__ WT, const float* __restrict__ bc,
        const int* __restrict__ batch, unsigned* __restrict__ g,
        int do_pool) {
    __shared__ h16 accS[8 * ASTRIDE];

    const int tid  = threadIdx.x;
    const int wave = tid >> 6;               // 0..15
    const int lane = tid & 63;
    const int node0 = blockIdx.x * 8;
    const int nl   = wave >> 1;              // node_local 0..7
    const int dir  = wave & 1;
    const int node = node0 + nl;
    const int q = lane & 15;
    const int s = lane >> 4;

    const int* ptr = dir ? colptrP : rowptrP;
    const int* deg = dir ? deg_in : deg_out;
    const int2* rec = dir ? recT : recA;

    float4 a = agg_dir(h_in, rec, ptr[node], deg[node], q * 8, s);
    if (s == 0) {
        h16x4 pk;
        pk.x = (h16)a.x; pk.y = (h16)a.y; pk.z = (h16)a.z; pk.w = (h16)a.w;
        *(h16x4*)(accS + nl * ASTRIDE + dir * 64 + q * 4) = pk;
    }
    __syncthreads();

    if (wave < 4) {
        const int nt = wave;                 // feature tile
        const int m = lane & 15, t = lane >> 4;
        float bb = bc[nt * 16 + m];
        h16x8 bfrag[4], afrag[4];
#pragma unroll
        for (int kk = 0; kk < 4; kk++) {
            bfrag[kk] = *(const h16x8*)(WT + (nt * 16 + m) * 128 + kk * 32 + t * 8);
            afrag[kk] = *(const h16x8*)(accS + (m & 7) * ASTRIDE + kk * 32 + t * 8);
        }
        f32x4 c = {0.f, 0.f, 0.f, 0.f};
#pragma unroll
        for (int kk = 0; kk < 4; kk++)
            c = __builtin_amdgcn_mfma_f32_16x16x32_f16(afrag[kk], bfrag[kk], c, 0, 0, 0);
        float ov[4];
#pragma unroll
        for (int r = 0; r < 4; r++)
            ov[r] = fmaxf(c[r] + bb, 0.0f);   // valid for rows t*4+r < 8 (t<2)
        if (do_pool) {
            int b0 = batch[node0], b7 = batch[node0 + 7];
            if (b0 == b7) {
                float mx = fmaxf(fmaxf(ov[0], ov[1]), fmaxf(ov[2], ov[3]));
                mx = fmaxf(mx, __shfl_xor(mx, 16));   // pair (t0,t1)
                if (t == 0)
                    atomicMax(&g[b0 * HDIM + nt * 16 + m], __float_as_uint(mx));
            } else if (t < 2) {
#pragma unroll
                for (int r = 0; r < 4; r++)
                    atomicMax(&g[batch[node0 + t * 4 + r] * HDIM + nt * 16 + m],
                              __float_as_uint(ov[r]));
            }
        } else if (t < 2) {
#pragma unroll
            for (int r = 0; r < 4; r++)
                *(h16*)(h_out + (size_t)(node0 + t * 4 + r) * 128
                        + (nt * 16 + m) * 2) = (h16)ov[r];
        }
    }
}

// -------------------------------------------------------------------- MLP head
__global__ __launch_bounds__(64) void mlp_kernel(const unsigned* __restrict__ g,
                                                 const float* __restrict__ wl1,
                                                 const float* __restrict__ bl1,
                                                 const float* __restrict__ wl2,
                                                 const float* __restrict__ bl2,
                                                 float* __restrict__ out) {
    int t = threadIdx.x;   // graph index, one block of 64
    float gv[HDIM];
#pragma unroll
    for (int k = 0; k < HDIM; k++) gv[k] = __uint_as_float(g[t * HDIM + k]);
    float o = bl2[0];
#pragma unroll
    for (int j = 0; j < 5; j++) {
        float hj = bl1[j];
#pragma unroll
        for (int k = 0; k < HDIM; k++) hj += gv[k] * wl1[k * 5 + j];
        hj = fmaxf(hj, 0.0f);
        o += hj * wl2[j];
    }
    out[t] = o;
}

// ------------------------------------------------------------------- launch
extern "C" void kernel_launch(void* const* d_in, const int* in_sizes, int n_in,
                              void* d_out, int out_size, void* d_ws, size_t ws_size,
                              hipStream_t stream) {
    const float* x   = (const float*)d_in[0];
    const int*   ei  = (const int*)d_in[1];
    const int*   bat = (const int*)d_in[2];
    const float* w1s = (const float*)d_in[3];
    const float* b1s = (const float*)d_in[4];
    const float* w1d = (const float*)d_in[5];
    const float* b1d = (const float*)d_in[6];
    const float* w2s = (const float*)d_in[7];
    const float* b2s = (const float*)d_in[8];
    const float* w2d = (const float*)d_in[9];
    const float* b2d = (const float*)d_in[10];
    const float* w3s = (const float*)d_in[11];
    const float* b3s = (const float*)d_in[12];
    const float* w3d = (const float*)d_in[13];
    const float* b3d = (const float*)d_in[14];
    const float* wl1 = (const float*)d_in[15];
    const float* bl1 = (const float*)d_in[16];
    const float* wl2 = (const float*)d_in[17];
    const float* bl2 = (const float*)d_in[18];
    float* out = (float*)d_out;

    // Workspace. bkt region (25.6MB) hosts hA (12.8MB) after scatter;
    // xh region (12.8MB) doubles as hB (xh dead after layer-1 agg).
    char* p = (char*)d_ws;
    int*   deg_out = (int*)p;              p += N_NODES * 4;
    int*   deg_in  = (int*)p;              p += N_NODES * 4;
    int*   rowptrP = (int*)p;              p += N_NODES * 4;
    int*   colptrP = (int*)p;              p += N_NODES * 4;
    float* r_out   = (float*)p;            p += N_NODES * 4;
    float* r_in    = (float*)p;            p += N_NODES * 4;
    int*   cntTabA = (int*)p;              p += (size_t)NB * NBLK * 4;
    int*   cntTabT = (int*)p;              p += (size_t)NB * NBLK * 4;
    int*   totTab  = (int*)p;              p += 1024 * 4;
    int*   bktStartA = (int*)p;            p += 512 * 4;
    int*   bktStartT = (int*)p;            p += 512 * 4;
    int2*  recA    = (int2*)p;             p += (size_t)EPAD * 8;
    int2*  recT    = (int2*)p;             p += (size_t)EPAD * 8;
    char*  hA      = p;                    // aliases bkt region
    int2*  bktA    = (int2*)p;
    int2*  bktT    = (int2*)(p + (size_t)N_EDGES * 8);
    p += 2 * (size_t)N_EDGES * 8;
    char*  xh      = p;                    // 12.8MB; doubles as hB
    char*  hB      = p;
    p += (size_t)N_NODES * 128;
    unsigned* g    = (unsigned*)p;         p += NGRAPH * HDIM * 4;
    h16*   WT      = (h16*)p;              p += 3 * 8192 * 2;
    float* bc      = (float*)p;            p += 3 * 64 * 4;

    cast_kernel<<<(N_NODES * 16 + 255) / 256, 256, 0, stream>>>(
        (const float4*)x, (h16x4*)xh, g);
    dim3 gw(32, 3);
    wprep_kernel<<<gw, 256, 0, stream>>>(w1s, w1d, w2s, w2d, w3s, w3d,
                                         b1s, b1d, b2s, b2d, b3s, b3d, WT, bc);

    bucket_count<<<NBLK, 512, 0, stream>>>(ei, cntTabA, cntTabT);
    dim3 gb2(NB, 2);
    chunk_scan<<<gb2, 256, 0, stream>>>(cntTabA, cntTabT, totTab);
    start_scan<<<1, 512, 0, stream>>>(totTab, bktStartA, bktStartT);
    bucketize_write<<<NBLK, 512, 0, stream>>>(ei, cntTabA, cntTabT,
                                              bktStartA, bktStartT, bktA, bktT);

    dim3 gb(NB, 2);
    bucket_deg_ptr<<<gb, 256, 0, stream>>>(bktStartA, bktStartT, bktA, bktT,
                                           deg_out, deg_in, r_out, r_in,
                                           rowptrP, colptrP);
    bucket_scatter<<<gb, 512, 0, stream>>>(
        rowptrP, colptrP, r_out, r_in, bktStartA, bktStartT, bktA, bktT, recA, recT);

    // Fused layers: xh -> hA -> hB -> pool
    layer_fused<<<NGROUPS, 1024, 0, stream>>>(
        xh, hA, rowptrP, deg_out, recA, colptrP, deg_in, recT,
        WT, bc, bat, g, 0);
    layer_fused<<<NGROUPS, 1024, 0, stream>>>(
        hA, hB, rowptrP, deg_out, recA, colptrP, deg_in, recT,
        WT + 8192, bc + 64, bat, g, 0);
    layer_fused<<<NGROUPS, 1024, 0, stream>>>(
        hB, hA, rowptrP, deg_out, recA, colptrP, deg_in, recT,
        WT + 16384, bc + 128, bat, g, 1);

    mlp_kernel<<<1, 64, 0, stream>>>(g, wl1, bl1, wl2, bl2, out);
}

// Round 17
// 491.326 us; speedup vs baseline: 1.1275x; 1.1275x over previous
//
#include <hip/hip_runtime.h>

// Problem constants
#define N_NODES 100000
#define N_EDGES 1600000
#define EPAD    (N_EDGES + NB * BW)      // rec capacity w/ per-bucket slack
#define HDIM    64
#define NGRAPH  64
#define BW      256                      // bucket width (nodes); shift = 8
#define NB      391                      // ceil(N_NODES / BW)
#define NBLK    256                      // edge-pass blocks
#define CHUNK   ((N_EDGES + NBLK - 1) / NBLK)
#define MTILES  (N_NODES / 16)           // 6250 GEMM m-tiles

// native fp16, no hip_fp16 header
typedef _Float16 h16;
typedef _Float16 h16x4 __attribute__((ext_vector_type(4)));
typedef _Float16 h16x8 __attribute__((ext_vector_type(8)));
typedef float    f32x4 __attribute__((ext_vector_type(4)));

// ----------------------------------------- K1: per-(block,bucket) edge counts
__global__ __launch_bounds__(512) void bucket_count(const int* __restrict__ ei,
                                                    int* __restrict__ cntTabA,
                                                    int* __restrict__ cntTabT) {
    __shared__ int cA[NB], cT[NB];
    const int tid = threadIdx.x;
    for (int i = tid; i < NB; i += 512) { cA[i] = 0; cT[i] = 0; }
    __syncthreads();
    const int e0 = blockIdx.x * CHUNK, e1 = min(e0 + CHUNK, N_EDGES);
    for (int e = e0 + tid; e < e1; e += 512) {
        int r = ei[e];
        int c = ei[N_EDGES + e];
        atomicAdd(&cA[r >> 8], 1);
        atomicAdd(&cT[c >> 8], 1);
    }
    __syncthreads();
    for (int b = tid; b < NB; b += 512) {
        cntTabA[b * NBLK + blockIdx.x] = cA[b];
        cntTabT[b * NBLK + blockIdx.x] = cT[b];
    }
}

// ---------------- K2a: per-bucket LDS scan of the 256 per-block counts
__global__ __launch_bounds__(256) void chunk_scan(int* __restrict__ cntTabA,
                                                  int* __restrict__ cntTabT,
                                                  int* __restrict__ tot) {
    __shared__ int s[256];
    const int b = blockIdx.x, d = blockIdx.y, tid = threadIdx.x;
    int* tab = d ? cntTabT : cntTabA;
    int v = tab[b * NBLK + tid];
    s[tid] = v;
    __syncthreads();
    for (int off = 1; off < 256; off <<= 1) {
        int t = (tid >= off) ? s[tid - off] : 0;
        __syncthreads();
        s[tid] += t;
        __syncthreads();
    }
    tab[b * NBLK + tid] = s[tid] - v;       // exclusive within bucket
    if (tid == 255) tot[d * 512 + b] = s[255];
}

// ---------------- K2b: bucket-start scan (both dirs, one block, parallel)
__global__ __launch_bounds__(512) void start_scan(const int* __restrict__ tot,
                                                  int* __restrict__ bktStartA,
                                                  int* __restrict__ bktStartT) {
    __shared__ int s[512];
    const int tid = threadIdx.x;
    int v = (tid < NB) ? tot[tid] : 0;
    s[tid] = v;
    __syncthreads();
    for (int off = 1; off < 512; off <<= 1) {
        int t = (tid >= off) ? s[tid - off] : 0;
        __syncthreads();
        s[tid] += t;
        __syncthreads();
    }
    if (tid < NB) bktStartA[tid] = s[tid] - v;
    if (tid == 0) bktStartA[NB] = N_EDGES;
    __syncthreads();
    int v2 = (tid < NB) ? tot[512 + tid] : 0;
    s[tid] = v2;
    __syncthreads();
    for (int off = 1; off < 512; off <<= 1) {
        int t = (tid >= off) ? s[tid - off] : 0;
        __syncthreads();
        s[tid] += t;
        __syncthreads();
    }
    if (tid < NB) bktStartT[tid] = s[tid] - v2;
    if (tid == 0) bktStartT[NB] = N_EDGES;
}

// --------------------------- K3: bucketize write (bases pre-reserved)
__global__ __launch_bounds__(512) void bucketize_write(const int* __restrict__ ei,
                                                       const int* __restrict__ cntTabA,
                                                       const int* __restrict__ cntTabT,
                                                       const int* __restrict__ bktStartA,
                                                       const int* __restrict__ bktStartT,
                                                       int2* __restrict__ bktA,
                                                       int2* __restrict__ bktT) {
    __shared__ int bA[NB], bT[NB];
    const int tid = threadIdx.x;
    for (int i = tid; i < NB; i += 512) {
        bA[i] = bktStartA[i] + cntTabA[i * NBLK + blockIdx.x];
        bT[i] = bktStartT[i] + cntTabT[i * NBLK + blockIdx.x];
    }
    __syncthreads();
    const int e0 = blockIdx.x * CHUNK, e1 = min(e0 + CHUNK, N_EDGES);
    for (int e = e0 + tid; e < e1; e += 512) {
        int r = ei[e];
        int c = ei[N_EDGES + e];
        int pA = atomicAdd(&bA[r >> 8], 1);
        bktA[pA] = make_int2(r, c);          // (target, source)
        int pT = atomicAdd(&bT[c >> 8], 1);
        bktT[pT] = make_int2(c, r);          // (target, source)
    }
}

// ----- K4: per-bucket degrees + rsqrt + padded node ptrs (slack allocation)
// rec region for bucket b starts at bktStart[b] + b*BW (pad slack <= BW),
// so node offsets need no cross-bucket scan.
__global__ __launch_bounds__(256) void bucket_deg_ptr(
        const int* __restrict__ bktStartA, const int* __restrict__ bktStartT,
        const int2* __restrict__ bktA, const int2* __restrict__ bktT,
        int* __restrict__ deg_out, int* __restrict__ deg_in,
        float* __restrict__ r_out, float* __restrict__ r_in,
        int* __restrict__ rowptrP, int* __restrict__ colptrP) {
    __shared__ int c[BW];
    __shared__ int s[256];
    const int b = blockIdx.x, d = blockIdx.y, tid = threadIdx.x;
    const int* bs = d ? bktStartT : bktStartA;
    const int2* bkt = d ? bktT : bktA;
    int* deg = d ? deg_in : deg_out;
    float* rr = d ? r_in : r_out;
    int* ptr = d ? colptrP : rowptrP;
    const int node0 = b * BW;
    c[tid] = 0;
    __syncthreads();
    const int i0 = bs[b], i1 = bs[b + 1];
    for (int i = i0 + tid; i < i1; i += 256) atomicAdd(&c[bkt[i].x - node0], 1);
    __syncthreads();
    int n = node0 + tid, dg = c[tid];
    int pad = dg + (dg & 1);
    if (n < N_NODES) {
        deg[n] = dg;
        rr[n] = dg > 0 ? rsqrtf((float)dg) : 0.0f;
    } else pad = 0;
    s[tid] = pad;
    __syncthreads();
    for (int off = 1; off < 256; off <<= 1) {
        int t = (tid >= off) ? s[tid - off] : 0;
        __syncthreads();
        s[tid] += t;
        __syncthreads();
    }
    if (n < N_NODES) ptr[n] = i0 + b * BW + (s[tid] - pad);
}

// ------------------------------------- K7: within-bucket counting scatter
// record payload: (src<<7, w fp32 bits)
__global__ __launch_bounds__(512) void bucket_scatter(
        const int* __restrict__ rowptrP, const int* __restrict__ colptrP,
        const float* __restrict__ r_out, const float* __restrict__ r_in,
        const int* __restrict__ bktStartA, const int* __restrict__ bktStartT,
        const int2* __restrict__ bktA, const int2* __restrict__ bktT,
        int2* __restrict__ recA, int2* __restrict__ recT) {
    __shared__ int cur[BW];
    __shared__ float rwt[BW];
    const int b = blockIdx.x, d = blockIdx.y, tid = threadIdx.x;
    const int* ptr = d ? colptrP : rowptrP;
    const float* rt = d ? r_in : r_out;       // target-side scale (bucket-local)
    const float* rs = d ? r_out : r_in;       // source-side scale (gathered)
    const int* bs = d ? bktStartT : bktStartA;
    const int2* bkt = d ? bktT : bktA;
    int2* rec = d ? recT : recA;
    const int node0 = b * BW;
    if (tid < BW) {
        int n = node0 + tid;
        cur[tid] = (n < N_NODES) ? ptr[n] : 0;
        rwt[tid] = (n < N_NODES) ? rt[n] : 0.0f;
    }
    __syncthreads();
    const int i0 = bs[b], i1 = bs[b + 1];
    for (int i = i0 + tid; i < i1; i += 512) {
        int2 e = bkt[i];
        float w = rwt[e.x - node0] * rs[e.y];
        int p = atomicAdd(&cur[e.x - node0], 1);
        rec[p] = make_int2(e.y << 7, __float_as_int(w));   // byte offset, weight
    }
}

// ---------------------------------------- x -> fp16 cast (+ zero pooled g)
__global__ __launch_bounds__(256) void cast_kernel(const float4* __restrict__ x,
                                                   h16x4* __restrict__ xh,
                                                   unsigned* __restrict__ g) {
    if (blockIdx.x == 0) {
        for (int j = threadIdx.x; j < NGRAPH * HDIM; j += 256) g[j] = 0u;
    }
    int i = blockIdx.x * 256 + threadIdx.x;   // over N*64/4 float4s
    if (i < N_NODES * 16) {
        float4 v = x[i];
        h16x4 o;
        o.x = (h16)v.x; o.y = (h16)v.y; o.z = (h16)v.z; o.w = (h16)v.w;
        xh[i] = o;
    }
}

// ------------------------- weight prep: WT[l][f][k] = 0.5*Wcat^T fp16, bcat
__global__ __launch_bounds__(256) void wprep_kernel(
        const float* __restrict__ w1s, const float* __restrict__ w1d,
        const float* __restrict__ w2s, const float* __restrict__ w2d,
        const float* __restrict__ w3s, const float* __restrict__ w3d,
        const float* __restrict__ b1s, const float* __restrict__ b1d,
        const float* __restrict__ b2s, const float* __restrict__ b2d,
        const float* __restrict__ b3s, const float* __restrict__ b3d,
        h16* __restrict__ WT, float* __restrict__ bc) {
    const int l = blockIdx.y;
    const float* ws = l == 0 ? w1s : l == 1 ? w2s : w3s;
    const float* wd = l == 0 ? w1d : l == 1 ? w2d : w3d;
    int e = blockIdx.x * 256 + threadIdx.x;
    if (e < 8192) {
        int f = e >> 7, k = e & 127;
        float v = (k < 64) ? ws[k * 64 + f] : wd[(k - 64) * 64 + f];
        WT[l * 8192 + f * 128 + k] = (h16)(0.5f * v);
    }
    if (blockIdx.x == 0 && threadIdx.x < 64) {
        const float* bs = l == 0 ? b1s : l == 1 ? b2s : b3s;
        const float* bd = l == 0 ? b1d : l == 1 ? b2d : b3d;
        bc[l * 64 + threadIdx.x] = 0.5f * (bs[threadIdx.x] + bd[threadIdx.x]);
    }
}

// ------------------------------------------------ aggregation (LDS-free)
__device__ __forceinline__ void fma4h(float4& a, float w, h16x4 f) {
    a.x = fmaf(w, (float)f.x, a.x);
    a.y = fmaf(w, (float)f.y, a.y);
    a.z = fmaf(w, (float)f.z, a.z);
    a.w = fmaf(w, (float)f.w, a.w);
}

__device__ __forceinline__ float4 red_s(float4 v) {
    v.x += __shfl_xor(v.x, 16); v.y += __shfl_xor(v.y, 16);
    v.z += __shfl_xor(v.z, 16); v.w += __shfl_xor(v.w, 16);
    v.x += __shfl_xor(v.x, 32); v.y += __shfl_xor(v.y, 32);
    v.z += __shfl_xor(v.z, 32); v.w += __shfl_xor(v.w, 32);
    return v;
}

__device__ __forceinline__ h16x4 ld_h4(const char* __restrict__ p) {
    return *(const h16x4*)p;
}

// per-wave aggregation; lane (q,s): q = feature quad, s = edge-pair slot.
// records hold src<<7 byte offsets (128B rows); node runs start 16B-aligned.
__device__ __forceinline__ float4 agg_dir(const char* __restrict__ hb,
                                          const int2* __restrict__ rec,
                                          int start, int deg, int q, int s) {
    float4 a0 = {0.f,0.f,0.f,0.f}, a1 = {0.f,0.f,0.f,0.f};
    float4 a2 = {0.f,0.f,0.f,0.f}, a3 = {0.f,0.f,0.f,0.f};
    const int4* rec4 = (const int4*)(rec + start);
    const int qb = q * 8;
    int k = 0;
    for (; k + 16 <= deg; k += 16) {
        int4 p0 = rec4[(k >> 1) + s];
        int4 p1 = rec4[(k >> 1) + 4 + s];
        h16x4 f0 = ld_h4(hb + p0.x + qb);
        h16x4 f1 = ld_h4(hb + p0.z + qb);
        h16x4 f2 = ld_h4(hb + p1.x + qb);
        h16x4 f3 = ld_h4(hb + p1.z + qb);
        fma4h(a0, __int_as_float(p0.y), f0);
        fma4h(a1, __int_as_float(p0.w), f1);
        fma4h(a2, __int_as_float(p1.y), f2);
        fma4h(a3, __int_as_float(p1.w), f3);
    }
    if (k + 8 <= deg) {
        int4 p = rec4[(k >> 1) + s];
        h16x4 f0 = ld_h4(hb + p.x + qb);
        h16x4 f1 = ld_h4(hb + p.z + qb);
        fma4h(a0, __int_as_float(p.y), f0);
        fma4h(a1, __int_as_float(p.w), f1);
        k += 8;
    }
    int r = deg - k;
    if (2 * s < r) {
        int4 p = rec4[(k >> 1) + s];
        h16x4 f0 = ld_h4(hb + p.x + qb);
        fma4h(a2, __int_as_float(p.y), f0);
        if (2 * s + 1 < r) {
            h16x4 f1 = ld_h4(hb + p.z + qb);
            fma4h(a3, __int_as_float(p.w), f1);
        }
    }
    a0.x += a1.x; a0.y += a1.y; a0.z += a1.z; a0.w += a1.w;
    a2.x += a3.x; a2.y += a3.y; a2.z += a3.z; a2.w += a3.w;
    a0.x += a2.x; a0.y += a2.y; a0.z += a2.z; a0.w += a2.w;
    return red_s(a0);
}

// no LDS, no barrier: one wave per (node, dir); dirs write disjoint halves.
__global__ __launch_bounds__(256) void agg_kernel(
        const char* __restrict__ h_in, char* __restrict__ acc_out, int sh,
        const int* __restrict__ rowptrP, const int* __restrict__ deg_out,
        const int2* __restrict__ recA,
        const int* __restrict__ colptrP, const int* __restrict__ deg_in,
        const int2* __restrict__ recT) {
    const int tid  = threadIdx.x;
    const int wid  = (blockIdx.x << 2) + (tid >> 6);   // global wave id
    const int lane = tid & 63;
    const int node = wid >> 1;
    const int dir  = wid & 1;
    const int q = lane & 15;
    const int s = lane >> 4;

    const int* ptr = dir ? colptrP : rowptrP;
    const int* deg = dir ? deg_in : deg_out;
    const int2* rec = dir ? recT : recA;

    // sh selects input row stride: 0 -> records' <<7 is exact (128B rows),
    // 1 -> double (256B acc rows) handled by scaling the offset.
    float4 a;
    if (sh == 0) {
        a = agg_dir(h_in, rec, ptr[node], deg[node], q, s);
    } else {
        // 256B rows: offsets in records are src<<7; multiply by 2 via shift
        // (done inside a modified loop would cost VALU; instead we pre-built
        // records as src<<7 and h rows are 256B only for acc buffers, which
        // are never gathered — h_out of gemm is always 128B rows.)
        a = agg_dir(h_in, rec, ptr[node], deg[node], q, s);
    }
    if (s == 0) {
        h16x4 pk;
        pk.x = (h16)a.x; pk.y = (h16)a.y; pk.z = (h16)a.z; pk.w = (h16)a.w;
        *(h16x4*)(acc_out + (size_t)node * 256 + dir * 128 + q * 8) = pk;
    }
}

// --------------------------------------- GEMM via MFMA
// acc rows are 256B ([128] fp16 A||T); h = ReLU(acc @ WT^T + bc) written to
// h_out (128B rows). Layer 3 (do_pool) fuses max-pool instead of storing.
__global__ __launch_bounds__(256) void gemm_kernel(const char* __restrict__ acc,
                                                   char* __restrict__ h_out,
                                                   const h16* __restrict__ WT,
                                                   const float* __restrict__ bc,
                                                   const int* __restrict__ batch,
                                                   unsigned* __restrict__ g,
                                                   int do_pool) {
    const int lane = threadIdx.x & 63;
    const int wid = (blockIdx.x * 256 + threadIdx.x) >> 6;
    const int nW = gridDim.x * 4;
    const int m = lane & 15, t = lane >> 4;

    h16x8 bfrag[4][4];
    float bb[4];
#pragma unroll
    for (int nt = 0; nt < 4; nt++) {
        bb[nt] = bc[nt * 16 + m];
#pragma unroll
        for (int kk = 0; kk < 4; kk++)
            bfrag[nt][kk] = *(const h16x8*)(WT + (nt * 16 + m) * 128 + kk * 32 + t * 8);
    }

    for (int tile = wid; tile < MTILES; tile += nW) {
        const char* arow = acc + (size_t)tile * 16 * 256;
        const int node0 = tile * 16;
        int b0 = 0, b15 = 0;
        if (do_pool) { b0 = batch[node0]; b15 = batch[node0 + 15]; }
        h16x8 afrag[4];
#pragma unroll
        for (int kk = 0; kk < 4; kk++)
            afrag[kk] = *(const h16x8*)(arow + m * 256 + kk * 64 + t * 16);
#pragma unroll
        for (int nt = 0; nt < 4; nt++) {
            f32x4 c = {0.f, 0.f, 0.f, 0.f};
#pragma unroll
            for (int kk = 0; kk < 4; kk++)
                c = __builtin_amdgcn_mfma_f32_16x16x32_f16(afrag[kk], bfrag[nt][kk], c, 0, 0, 0);
            float ov[4];
#pragma unroll
            for (int r = 0; r < 4; r++)
                ov[r] = fmaxf(c[r] + bb[nt], 0.0f);
            if (do_pool) {
                if (b0 == b15) {
                    float mx = fmaxf(fmaxf(ov[0], ov[1]), fmaxf(ov[2], ov[3]));
                    mx = fmaxf(mx, __shfl_xor(mx, 16));
                    mx = fmaxf(mx, __shfl_xor(mx, 32));
                    if (t == 0)
                        atomicMax(&g[b0 * HDIM + nt * 16 + m], __float_as_uint(mx));
                } else {
#pragma unroll
                    for (int r = 0; r < 4; r++)
                        atomicMax(&g[batch[node0 + t * 4 + r] * HDIM + nt * 16 + m],
                                  __float_as_uint(ov[r]));
                }
            } else {
#pragma unroll
                for (int r = 0; r < 4; r++)
                    *(h16*)(h_out + (size_t)(node0 + t * 4 + r) * 128
                            + (nt * 16 + m) * 2) = (h16)ov[r];
            }
        }
    }
}

// -------------------------------------------------------------------- MLP head
__global__ __launch_bounds__(64) void mlp_kernel(const unsigned* __restrict__ g,
                                                 const float* __restrict__ wl1,
                                                 const float* __restrict__ bl1,
                                                 const float* __restrict__ wl2,
                                                 const float* __restrict__ bl2,
                                                 float* __restrict__ out) {
    int t = threadIdx.x;   // graph index, one block of 64
    float gv[HDIM];
#pragma unroll
    for (int k = 0; k < HDIM; k++) gv[k] = __uint_as_float(g[t * HDIM + k]);
    float o = bl2[0];
#pragma unroll
    for (int j = 0; j < 5; j++) {
        float hj = bl1[j];
#pragma unroll
        for (int k = 0; k < HDIM; k++) hj += gv[k] * wl1[k * 5 + j];
        hj = fmaxf(hj, 0.0f);
        o += hj * wl2[j];
    }
    out[t] = o;
}

// ------------------------------------------------------------------- launch
extern "C" void kernel_launch(void* const* d_in, const int* in_sizes, int n_in,
                              void* d_out, int out_size, void* d_ws, size_t ws_size,
                              hipStream_t stream) {
    const float* x   = (const float*)d_in[0];
    const int*   ei  = (const int*)d_in[1];
    const int*   bat = (const int*)d_in[2];
    const float* w1s = (const float*)d_in[3];
    const float* b1s = (const float*)d_in[4];
    const float* w1d = (const float*)d_in[5];
    const float* b1d = (const float*)d_in[6];
    const float* w2s = (const float*)d_in[7];
    const float* b2s = (const float*)d_in[8];
    const float* w2d = (const float*)d_in[9];
    const float* b2d = (const float*)d_in[10];
    const float* w3s = (const float*)d_in[11];
    const float* b3s = (const float*)d_in[12];
    const float* w3d = (const float*)d_in[13];
    const float* b3d = (const float*)d_in[14];
    const float* wl1 = (const float*)d_in[15];
    const float* bl1 = (const float*)d_in[16];
    const float* wl2 = (const float*)d_in[17];
    const float* bl2 = (const float*)d_in[18];
    float* out = (float*)d_out;

    // Workspace. bkt region (25.6MB) hosts accP+hA after scatter; second
    // 25.6MB region: accQ + (xh | hB).
    char* p = (char*)d_ws;
    int*   deg_out = (int*)p;              p += N_NODES * 4;
    int*   deg_in  = (int*)p;              p += N_NODES * 4;
    int*   rowptrP = (int*)p;              p += N_NODES * 4;
    int*   colptrP = (int*)p;              p += N_NODES * 4;
    float* r_out   = (float*)p;            p += N_NODES * 4;
    float* r_in    = (float*)p;            p += N_NODES * 4;
    int*   cntTabA = (int*)p;              p += (size_t)NB * NBLK * 4;
    int*   cntTabT = (int*)p;              p += (size_t)NB * NBLK * 4;
    int*   totTab  = (int*)p;              p += 1024 * 4;
    int*   bktStartA = (int*)p;            p += 512 * 4;
    int*   bktStartT = (int*)p;            p += 512 * 4;
    int2*  recA    = (int2*)p;             p += (size_t)EPAD * 8;
    int2*  recT    = (int2*)p;             p += (size_t)EPAD * 8;
    char*  regP    = p;                    // 25.6MB: bktA|bktT, then acc (256B rows)
    int2*  bktA    = (int2*)p;
    int2*  bktT    = (int2*)(p + (size_t)N_EDGES * 8);
    char*  accP    = p;
    p += 2 * (size_t)N_EDGES * 8;
    char*  xh      = p;                    // 12.8MB (128B rows); doubles as hA
    char*  hA      = p;
    p += (size_t)N_NODES * 128;
    char*  hB      = p;                    // 12.8MB (128B rows)
    p += (size_t)N_NODES * 128;
    unsigned* g    = (unsigned*)p;         p += NGRAPH * HDIM * 4;
    h16*   WT      = (h16*)p;              p += 3 * 8192 * 2;
    float* bc      = (float*)p;            p += 3 * 64 * 4;

    cast_kernel<<<(N_NODES * 16 + 255) / 256, 256, 0, stream>>>(
        (const float4*)x, (h16x4*)xh, g);
    dim3 gw(32, 3);
    wprep_kernel<<<gw, 256, 0, stream>>>(w1s, w1d, w2s, w2d, w3s, w3d,
                                         b1s, b1d, b2s, b2d, b3s, b3d, WT, bc);

    bucket_count<<<NBLK, 512, 0, stream>>>(ei, cntTabA, cntTabT);
    dim3 gb2(NB, 2);
    chunk_scan<<<gb2, 256, 0, stream>>>(cntTabA, cntTabT, totTab);
    start_scan<<<1, 512, 0, stream>>>(totTab, bktStartA, bktStartT);
    bucketize_write<<<NBLK, 512, 0, stream>>>(ei, cntTabA, cntTabT,
                                              bktStartA, bktStartT, bktA, bktT);

    dim3 gb(NB, 2);
    bucket_deg_ptr<<<gb, 256, 0, stream>>>(bktStartA, bktStartT, bktA, bktT,
                                           deg_out, deg_in, r_out, r_in,
                                           rowptrP, colptrP);
    bucket_scatter<<<gb, 512, 0, stream>>>(
        rowptrP, colptrP, r_out, r_in, bktStartA, bktStartT, bktA, bktT, recA, recT);

    const int agrid = N_NODES * 2 / 4;    // one wave per (node,dir), 4 waves/block
    // Layer 1: xh -> accP (bkt dead) -> hB
    agg_kernel<<<agrid, 256, 0, stream>>>(xh, accP, 0,
                                          rowptrP, deg_out, recA, colptrP, deg_in, recT);
    gemm_kernel<<<256, 256, 0, stream>>>(accP, hB, WT, bc, bat, g, 0);
    // Layer 2: hB -> accP -> hA (xh dead)
    agg_kernel<<<agrid, 256, 0, stream>>>(hB, accP, 0,
                                          rowptrP, deg_out, recA, colptrP, deg_in, recT);
    gemm_kernel<<<256, 256, 0, stream>>>(accP, hA, WT + 8192, bc + 64, bat, g, 0);
    // Layer 3: hA -> accP -> fused max-pool
    agg_kernel<<<agrid, 256, 0, stream>>>(hA, accP, 0,
                                          rowptrP, deg_out, recA, colptrP, deg_in, recT);
    gemm_kernel<<<256, 256, 0, stream>>>(accP, hB, WT + 16384, bc + 128, bat, g, 1);

    mlp_kernel<<<1, 64, 0, stream>>>(g, wl1, bl1, wl2, bl2, out);
}